// Round 5
// baseline (760.396 us; speedup 1.0000x reference)
//
#include <hip/hip_runtime.h>
#include <hip/hip_bf16.h>
#include <math.h>

typedef unsigned short u16;
typedef unsigned int u32;
typedef short s16x8 __attribute__((ext_vector_type(8)));
typedef float f32x4 __attribute__((ext_vector_type(4)));

// Problem constants
#define TTOK 2048
#define HDIM 2048
#define ENUM 32
#define IDIM 768
#define KTOP 4

// Workspace layout (bytes)
#define WS_XB   0L                         // u16[2048*2048]  x in bf16       (8 MB)
#define WS_ACT  8388608L                   // u16[8192*768]   act bf16        (12.6 MB)
#define WS_TIDX 20971520L                  // int[8192] topk expert idx
#define WS_TW   (WS_TIDX + 32768L)         // float[8192] topk weights
#define WS_CNT  (WS_TW + 32768L)           // int[32] counts
#define WS_OFFS (WS_CNT + 128L)            // int[33] offsets
#define WS_CUR  (WS_OFFS + 256L)           // int[32] cursors
#define WS_RTOK (WS_CUR + 128L)            // int[8192] row -> token
#define WS_RW   (WS_RTOK + 32768L)         // float[8192] row -> routing weight

// B LDS row stride: 72 u16 = 144B = 36 dwords (64k + 8 pad). 36 = 4 mod 32
// -> b128 reads/b32 writes land 2 lanes/bank (free structural minimum).
#define LDB 72

__device__ __forceinline__ u16 f2bf(float f) {
  unsigned u = __builtin_bit_cast(unsigned, f);
  unsigned r = (u + 0x7fffu + ((u >> 16) & 1u)) >> 16;
  return (u16)r;
}
__device__ __forceinline__ unsigned pk2(float a, float b) {
  return (unsigned)f2bf(a) | ((unsigned)f2bf(b) << 16);
}

// ---------------- x f32 -> bf16 ----------------
__global__ __launch_bounds__(256) void cvt_x_kernel(const float* __restrict__ x,
                                                    u16* __restrict__ xb) {
  long i = ((long)blockIdx.x * 256 + threadIdx.x) * 8;
  float4 a = *(const float4*)(x + i);
  float4 b = *(const float4*)(x + i + 4);
  uint4 o;
  o.x = pk2(a.x, a.y);
  o.y = pk2(a.z, a.w);
  o.z = pk2(b.x, b.y);
  o.w = pk2(b.z, b.w);
  *(uint4*)(xb + i) = o;
}

// ---------------- router ----------------
__global__ __launch_bounds__(256) void router_kernel(const float* __restrict__ x,
                                                     const float* __restrict__ gw,
                                                     int* __restrict__ tidx,
                                                     float* __restrict__ tw,
                                                     int* __restrict__ counts) {
  __shared__ float xs[HDIM];
  __shared__ float part[256];
  __shared__ float lg[ENUM];
  int t = blockIdx.x;
  const float4* xr = (const float4*)(x + (long)t * HDIM);
  float4* xs4 = (float4*)xs;
  for (int i = threadIdx.x; i < HDIM / 4; i += 256) xs4[i] = xr[i];
  __syncthreads();
  int e = threadIdx.x >> 3, ch = threadIdx.x & 7;
  const float4* gp = (const float4*)(gw + (long)e * HDIM + ch * 256);
  const float4* xp = (const float4*)(xs + ch * 256);
  float s = 0.f;
#pragma unroll 8
  for (int c = 0; c < 64; c++) {
    float4 gv = gp[c], xv = xp[c];
    s += gv.x * xv.x + gv.y * xv.y + gv.z * xv.z + gv.w * xv.w;
  }
  part[threadIdx.x] = s;
  __syncthreads();
  if (threadIdx.x < 32) {
    float v = 0.f;
#pragma unroll
    for (int j = 0; j < 8; j++) v += part[threadIdx.x * 8 + j];
    lg[threadIdx.x] = v;
  }
  __syncthreads();
  if (threadIdx.x == 0) {
    int sel[KTOP]; float sv[KTOP];
    unsigned mask = 0;
    for (int k = 0; k < KTOP; k++) {
      float best = -INFINITY; int bi = 0;
      for (int j = 0; j < ENUM; j++)
        if (!((mask >> j) & 1u) && lg[j] > best) { best = lg[j]; bi = j; }
      mask |= 1u << bi; sel[k] = bi; sv[k] = best;
    }
    float m = sv[0], den = 0.f, ex[KTOP];
    for (int k = 0; k < KTOP; k++) { ex[k] = expf(sv[k] - m); den += ex[k]; }
    for (int k = 0; k < KTOP; k++) {
      tidx[t * KTOP + k] = sel[k];
      tw[t * KTOP + k] = ex[k] / den;
      atomicAdd(&counts[sel[k]], 1);
    }
  }
}

// ---------------- scan ----------------
__global__ void scan_kernel(const int* __restrict__ counts, int* __restrict__ offs,
                            int* __restrict__ cur) {
  if (threadIdx.x == 0) {
    int a = 0;
    for (int e = 0; e < ENUM; e++) { offs[e] = a; a += counts[e]; }
    offs[ENUM] = a;
  }
  if (threadIdx.x < ENUM) cur[threadIdx.x] = 0;
}

// ---------------- scatter ----------------
__global__ __launch_bounds__(256) void scatter_kernel(const int* __restrict__ tidx,
                                                      const float* __restrict__ tw,
                                                      const int* __restrict__ offs,
                                                      int* __restrict__ cur,
                                                      int* __restrict__ rtok,
                                                      float* __restrict__ rw) {
  int i = blockIdx.x * 256 + threadIdx.x;
  int e = tidx[i];
  int pos = atomicAdd(&cur[e], 1);
  int row = offs[e] + pos;
  rtok[row] = i >> 2;
  rw[row] = tw[i];
}

// ================= GEMM1: act = silu(x Wg) * (x Wu) =================
// BM=256, BN=32, BK=64, 512 thr (8 waves, 4m x 2n; wave = 64 rows x 16 cols
// of each of the 2 mats). A-fragments read DIRECTLY from global (xb is
// L2/L3-resident); only B (f32 weights -> bf16 transposed) staged in LDS,
// double-buffered. 16 MFMA / wave / step, NS = 32 steps.
__global__ __launch_bounds__(512, 4) void gemm1_kernel(const u16* __restrict__ xb,
                                                       const float* __restrict__ wgp,
                                                       const float* __restrict__ wup,
                                                       const int* __restrict__ offs,
                                                       const int* __restrict__ rtok,
                                                       u16* __restrict__ act) {
  int d = blockIdx.x;
  int e = d & 31;
  int nt = (d >> 5) % 24;          // 24 n-tiles of 32 (IDIM=768)
  int mt = d / 768;                // 0..7
  int off = offs[e], cnt = offs[e + 1] - off;
  int m0 = mt << 8;
  if (m0 >= cnt) return;
  int rows = cnt - m0; if (rows > 256) rows = 256;
  int baser = off + m0;
  int n0 = nt << 5;

  __shared__ __align__(16) u16 Bs[2][2][32 * LDB];   // 18.4 KB

  int tid = threadIdx.x;
  int ln = tid & 63;
  int wv = tid >> 6;
  int wm = wv >> 1, wn = wv & 1;   // 4m x 2n
  int lhi = ln >> 4, llo = ln & 15;

  // ---- A: per-lane global byte offsets for the 4 row-fragments ----
  const char* xbb = (const char*)xb;
  long aOff[4];
#pragma unroll
  for (int mf = 0; mf < 4; mf++) {
    int rl = wm * 64 + mf * 16 + llo;
    if (rl >= rows) rl = rows - 1;
    aOff[mf] = (long)rtok[baser + rl] * (HDIM * 2) + lhi * 16;
  }

  // ---- B staging: mat = tid>>8 (0 gate, 1 up); lanes along K ----
  int mat = tid >> 8;
  int qk = tid & 31;               // k-pair: rows 2qk, 2qk+1
  int g4 = (tid >> 5) & 7;         // n-chunk of 4: cols 4g4..4g4+3
  const float* bSrc = (mat ? wup : wgp) + (long)e * (HDIM * IDIM) +
                      (long)(2 * qk) * IDIM + n0 + 4 * g4;
  u16* bD0 = &Bs[0][mat][(4 * g4) * LDB + 2 * qk];
  u16* bD1 = &Bs[1][mat][(4 * g4) * LDB + 2 * qk];

  f32x4 accg[4], accu[4];
  f32x4 zz = {0.f, 0.f, 0.f, 0.f};
#pragma unroll
  for (int a = 0; a < 4; a++) { accg[a] = zz; accu[a] = zz; }

  float4 rB0, rB1;

#define LOADB(t)                                                     \
  {                                                                  \
    const float* bp = bSrc + (long)(t) * 64 * IDIM;                  \
    rB0 = *(const float4*)bp;                                        \
    rB1 = *(const float4*)(bp + IDIM);                               \
  }
#define WRITEB(buf)                                                  \
  {                                                                  \
    u16* bd = buf ? bD1 : bD0;                                       \
    *(u32*)(bd + 0 * LDB) = pk2(rB0.x, rB1.x);                       \
    *(u32*)(bd + 1 * LDB) = pk2(rB0.y, rB1.y);                       \
    *(u32*)(bd + 2 * LDB) = pk2(rB0.z, rB1.z);                       \
    *(u32*)(bd + 3 * LDB) = pk2(rB0.w, rB1.w);                       \
  }

  const int NS = HDIM / 64;  // 32
  LOADB(0);
  WRITEB(0);
  LOADB(1);
  __syncthreads();

  int cb = (wn * 16 + llo) * LDB;  // B col row base (u16)
  for (int t = 0; t < NS; ++t) {
    int cur = t & 1;
    if (t + 1 < NS) WRITEB(cur ^ 1);
    if (t + 2 < NS) LOADB(t + 2);
    {
      const u16* Bg = Bs[cur][0];
      const u16* Bu = Bs[cur][1];
      long k0b = (long)t * 128;    // 64 k * 2B
      s16x8 a0[4], a1[4];
#pragma unroll
      for (int mf = 0; mf < 4; mf++)
        a0[mf] = *(const s16x8*)(xbb + aOff[mf] + k0b);
      s16x8 bg0 = *(const s16x8*)&Bg[cb + lhi * 8];
      s16x8 bu0 = *(const s16x8*)&Bu[cb + lhi * 8];
#pragma unroll
      for (int mf = 0; mf < 4; mf++)
        a1[mf] = *(const s16x8*)(xbb + aOff[mf] + k0b + 64);
      s16x8 bg1 = *(const s16x8*)&Bg[cb + 32 + lhi * 8];
      s16x8 bu1 = *(const s16x8*)&Bu[cb + 32 + lhi * 8];
#pragma unroll
      for (int mf = 0; mf < 4; mf++)
        accg[mf] = __builtin_amdgcn_mfma_f32_16x16x32_bf16(a0[mf], bg0, accg[mf], 0, 0, 0);
#pragma unroll
      for (int mf = 0; mf < 4; mf++)
        accu[mf] = __builtin_amdgcn_mfma_f32_16x16x32_bf16(a0[mf], bu0, accu[mf], 0, 0, 0);
#pragma unroll
      for (int mf = 0; mf < 4; mf++)
        accg[mf] = __builtin_amdgcn_mfma_f32_16x16x32_bf16(a1[mf], bg1, accg[mf], 0, 0, 0);
#pragma unroll
      for (int mf = 0; mf < 4; mf++)
        accu[mf] = __builtin_amdgcn_mfma_f32_16x16x32_bf16(a1[mf], bu1, accu[mf], 0, 0, 0);
    }
    __syncthreads();
  }

  // epilogue: silu(g)*u -> bf16 act
  int rb = wm * 64 + lhi * 4;
  int cb2 = n0 + wn * 16 + llo;
#pragma unroll
  for (int mf = 0; mf < 4; mf++) {
#pragma unroll
    for (int r4 = 0; r4 < 4; r4++) {
      int rl = rb + mf * 16 + r4;
      if (rl < rows) {
        float g = accg[mf][r4], u = accu[mf][r4];
        float av = g / (1.f + __expf(-g)) * u;
        act[(long)(baser + rl) * IDIM + cb2] = f2bf(av);
      }
    }
  }
#undef LOADB
#undef WRITEB
}

// ================= GEMM2: out[tok] += w * (act Wd) =================
// BM=256, BN=32, BK=64, 512 thr (8 waves, 4m x 2n). A (act, bf16,
// L3-resident, contiguous rows) read directly from global; B (wdown f32)
// staged bf16-transposed in LDS, double-buffered. NS = 12 steps.
__global__ __launch_bounds__(512, 4) void gemm2_kernel(const u16* __restrict__ act,
                                                       const float* __restrict__ wdp,
                                                       const int* __restrict__ offs,
                                                       const int* __restrict__ rtok,
                                                       const float* __restrict__ rw,
                                                       float* __restrict__ out) {
  int d = blockIdx.x;
  int e = d & 31;
  int nt = (d >> 5) & 63;          // 64 n-tiles of 32 (HDIM=2048)
  int mt = d >> 11;                // 0..7
  int off = offs[e], cnt = offs[e + 1] - off;
  int m0 = mt << 8;
  if (m0 >= cnt) return;
  int rows = cnt - m0; if (rows > 256) rows = 256;
  int baser = off + m0;
  int n0 = nt << 5;

  __shared__ __align__(16) u16 Bs[2][32 * LDB];   // 9.2 KB

  int tid = threadIdx.x;
  int ln = tid & 63;
  int wv = tid >> 6;
  int wm = wv >> 1, wn = wv & 1;
  int lhi = ln >> 4, llo = ln & 15;

  const char* ab = (const char*)act;
  long aOff[4];
#pragma unroll
  for (int mf = 0; mf < 4; mf++) {
    int rl = wm * 64 + mf * 16 + llo;
    if (rl >= rows) rl = rows - 1;
    aOff[mf] = (long)(baser + rl) * (IDIM * 2) + lhi * 16;
  }

  // B staging: threads 0..255, lanes along K
  int isB = (tid < 256);
  int qk = tid & 31;
  int g4 = (tid >> 5) & 7;
  const float* bSrc = wdp + (long)e * (IDIM * HDIM) + (long)(2 * qk) * HDIM + n0 + 4 * g4;
  u16* bD0 = &Bs[0][(4 * g4) * LDB + 2 * qk];
  u16* bD1 = &Bs[1][(4 * g4) * LDB + 2 * qk];

  f32x4 acc[4];
  f32x4 zz = {0.f, 0.f, 0.f, 0.f};
#pragma unroll
  for (int a = 0; a < 4; a++) acc[a] = zz;

  float4 rB0, rB1;

#define LOADB(t)                                                     \
  {                                                                  \
    if (isB) {                                                       \
      const float* bp = bSrc + (long)(t) * 64 * HDIM;                \
      rB0 = *(const float4*)bp;                                      \
      rB1 = *(const float4*)(bp + HDIM);                             \
    }                                                                \
  }
#define WRITEB(buf)                                                  \
  {                                                                  \
    if (isB) {                                                       \
      u16* bd = buf ? bD1 : bD0;                                     \
      *(u32*)(bd + 0 * LDB) = pk2(rB0.x, rB1.x);                     \
      *(u32*)(bd + 1 * LDB) = pk2(rB0.y, rB1.y);                     \
      *(u32*)(bd + 2 * LDB) = pk2(rB0.z, rB1.z);                     \
      *(u32*)(bd + 3 * LDB) = pk2(rB0.w, rB1.w);                     \
    }                                                                \
  }

  const int NS = IDIM / 64;  // 12
  LOADB(0);
  WRITEB(0);
  LOADB(1);
  __syncthreads();

  int cb = (wn * 16 + llo) * LDB;
  for (int t = 0; t < NS; ++t) {
    int cur = t & 1;
    if (t + 1 < NS) WRITEB(cur ^ 1);
    if (t + 2 < NS) LOADB(t + 2);
    {
      const u16* Bb = Bs[cur];
      long k0b = (long)t * 128;
      s16x8 a0[4], a1[4];
#pragma unroll
      for (int mf = 0; mf < 4; mf++)
        a0[mf] = *(const s16x8*)(ab + aOff[mf] + k0b);
      s16x8 b0 = *(const s16x8*)&Bb[cb + lhi * 8];
#pragma unroll
      for (int mf = 0; mf < 4; mf++)
        a1[mf] = *(const s16x8*)(ab + aOff[mf] + k0b + 64);
      s16x8 b1 = *(const s16x8*)&Bb[cb + 32 + lhi * 8];
#pragma unroll
      for (int mf = 0; mf < 4; mf++)
        acc[mf] = __builtin_amdgcn_mfma_f32_16x16x32_bf16(a0[mf], b0, acc[mf], 0, 0, 0);
#pragma unroll
      for (int mf = 0; mf < 4; mf++)
        acc[mf] = __builtin_amdgcn_mfma_f32_16x16x32_bf16(a1[mf], b1, acc[mf], 0, 0, 0);
    }
    __syncthreads();
  }

  // epilogue: scale by routing weight, atomic add into out
  int rb = wm * 64 + lhi * 4;
  int cb2 = n0 + wn * 16 + llo;
#pragma unroll
  for (int mf = 0; mf < 4; mf++) {
#pragma unroll
    for (int r4 = 0; r4 < 4; r4++) {
      int rl = rb + mf * 16 + r4;
      if (rl < rows) {
        int rr = baser + rl;
        atomicAdd(&out[(long)rtok[rr] * HDIM + cb2], acc[mf][r4] * rw[rr]);
      }
    }
  }
#undef LOADB
#undef WRITEB
}

extern "C" void kernel_launch(void* const* d_in, const int* in_sizes, int n_in,
                              void* d_out, int out_size, void* d_ws, size_t ws_size,
                              hipStream_t stream) {
  const float* x = (const float*)d_in[0];
  const float* gw = (const float*)d_in[1];
  const float* wgate = (const float*)d_in[2];
  const float* wup = (const float*)d_in[3];
  const float* wdown = (const float*)d_in[4];
  float* out = (float*)d_out;

  char* ws = (char*)d_ws;
  u16* xb = (u16*)(ws + WS_XB);
  u16* act = (u16*)(ws + WS_ACT);
  int* tidx = (int*)(ws + WS_TIDX);
  float* tw = (float*)(ws + WS_TW);
  int* cnt = (int*)(ws + WS_CNT);
  int* offs = (int*)(ws + WS_OFFS);
  int* cur = (int*)(ws + WS_CUR);
  int* rtok = (int*)(ws + WS_RTOK);
  float* rw = (float*)(ws + WS_RW);

  hipMemsetAsync(cnt, 0, 128, stream);
  hipMemsetAsync(d_out, 0, (size_t)out_size * sizeof(float), stream);

  hipLaunchKernelGGL(cvt_x_kernel, dim3(TTOK * HDIM / (256 * 8)), dim3(256), 0, stream, x, xb);
  hipLaunchKernelGGL(router_kernel, dim3(TTOK), dim3(256), 0, stream, x, gw, tidx, tw, cnt);
  hipLaunchKernelGGL(scan_kernel, dim3(1), dim3(64), 0, stream, cnt, offs, cur);
  hipLaunchKernelGGL(scatter_kernel, dim3(TTOK * KTOP / 256), dim3(256), 0, stream, tidx, tw, offs, cur, rtok, rw);
  hipLaunchKernelGGL(gemm1_kernel, dim3(32 * 24 * 8), dim3(512), 0, stream, xb, wgate, wup, offs, rtok, act);
  hipLaunchKernelGGL(gemm2_kernel, dim3(32 * 64 * 8), dim3(512), 0, stream, act, wdown, offs, rtok, rw, out);
}

// Round 6
// 585.252 us; speedup vs baseline: 1.2993x; 1.2993x over previous
//
#include <hip/hip_runtime.h>
#include <hip/hip_bf16.h>
#include <math.h>

typedef unsigned short u16;
typedef unsigned int u32;
typedef short s16x8 __attribute__((ext_vector_type(8)));
typedef unsigned short u16x8 __attribute__((ext_vector_type(8)));
typedef float f32x4 __attribute__((ext_vector_type(4)));

// Problem constants
#define TTOK 2048
#define HDIM 2048
#define ENUM 32
#define IDIM 768
#define KTOP 4

// Workspace layout (bytes)
#define WS_XB   0L                         // u16[2048*2048]  x in bf16       (8 MB)
#define WS_ACT  8388608L                   // u16[8192*768]   act bf16        (12.6 MB)
#define WS_TIDX 20971520L                  // int[8192] topk expert idx
#define WS_TW   (WS_TIDX + 32768L)         // float[8192] topk weights
#define WS_CNT  (WS_TW + 32768L)           // int[32] counts
#define WS_OFFS (WS_CNT + 128L)            // int[33] offsets
#define WS_CUR  (WS_OFFS + 256L)           // int[32] cursors
#define WS_RTOK (WS_CUR + 128L)            // int[8192] row -> token
#define WS_RW   (WS_RTOK + 32768L)         // float[8192] row -> routing weight

#define LDB 72   // B LDS row stride in u16 (144B): b128 reads 2-way (free)

__device__ __forceinline__ u16 f2bf(float f) {
  unsigned u = __builtin_bit_cast(unsigned, f);
  unsigned r = (u + 0x7fffu + ((u >> 16) & 1u)) >> 16;
  return (u16)r;
}
__device__ __forceinline__ unsigned pk2(float a, float b) {
  return (unsigned)f2bf(a) | ((unsigned)f2bf(b) << 16);
}

// ---------------- x f32 -> bf16 ----------------
__global__ __launch_bounds__(256) void cvt_x_kernel(const float* __restrict__ x,
                                                    u16* __restrict__ xb) {
  long i = ((long)blockIdx.x * 256 + threadIdx.x) * 8;
  float4 a = *(const float4*)(x + i);
  float4 b = *(const float4*)(x + i + 4);
  uint4 o;
  o.x = pk2(a.x, a.y);
  o.y = pk2(a.z, a.w);
  o.z = pk2(b.x, b.y);
  o.w = pk2(b.z, b.w);
  *(uint4*)(xb + i) = o;
}

// ---------------- router ----------------
__global__ __launch_bounds__(256) void router_kernel(const float* __restrict__ x,
                                                     const float* __restrict__ gw,
                                                     int* __restrict__ tidx,
                                                     float* __restrict__ tw,
                                                     int* __restrict__ counts) {
  __shared__ float xs[HDIM];
  __shared__ float part[256];
  __shared__ float lg[ENUM];
  int t = blockIdx.x;
  const float4* xr = (const float4*)(x + (long)t * HDIM);
  float4* xs4 = (float4*)xs;
  for (int i = threadIdx.x; i < HDIM / 4; i += 256) xs4[i] = xr[i];
  __syncthreads();
  int e = threadIdx.x >> 3, ch = threadIdx.x & 7;
  const float4* gp = (const float4*)(gw + (long)e * HDIM + ch * 256);
  const float4* xp = (const float4*)(xs + ch * 256);
  float s = 0.f;
#pragma unroll 8
  for (int c = 0; c < 64; c++) {
    float4 gv = gp[c], xv = xp[c];
    s += gv.x * xv.x + gv.y * xv.y + gv.z * xv.z + gv.w * xv.w;
  }
  part[threadIdx.x] = s;
  __syncthreads();
  if (threadIdx.x < 32) {
    float v = 0.f;
#pragma unroll
    for (int j = 0; j < 8; j++) v += part[threadIdx.x * 8 + j];
    lg[threadIdx.x] = v;
  }
  __syncthreads();
  if (threadIdx.x == 0) {
    int sel[KTOP]; float sv[KTOP];
    unsigned mask = 0;
    for (int k = 0; k < KTOP; k++) {
      float best = -INFINITY; int bi = 0;
      for (int j = 0; j < ENUM; j++)
        if (!((mask >> j) & 1u) && lg[j] > best) { best = lg[j]; bi = j; }
      mask |= 1u << bi; sel[k] = bi; sv[k] = best;
    }
    float m = sv[0], den = 0.f, ex[KTOP];
    for (int k = 0; k < KTOP; k++) { ex[k] = expf(sv[k] - m); den += ex[k]; }
    for (int k = 0; k < KTOP; k++) {
      tidx[t * KTOP + k] = sel[k];
      tw[t * KTOP + k] = ex[k] / den;
      atomicAdd(&counts[sel[k]], 1);
    }
  }
}

// ---------------- scan ----------------
__global__ void scan_kernel(const int* __restrict__ counts, int* __restrict__ offs,
                            int* __restrict__ cur) {
  if (threadIdx.x == 0) {
    int a = 0;
    for (int e = 0; e < ENUM; e++) { offs[e] = a; a += counts[e]; }
    offs[ENUM] = a;
  }
  if (threadIdx.x < ENUM) cur[threadIdx.x] = 0;
}

// ---------------- scatter ----------------
__global__ __launch_bounds__(256) void scatter_kernel(const int* __restrict__ tidx,
                                                      const float* __restrict__ tw,
                                                      const int* __restrict__ offs,
                                                      int* __restrict__ cur,
                                                      int* __restrict__ rtok,
                                                      float* __restrict__ rw) {
  int i = blockIdx.x * 256 + threadIdx.x;
  int e = tidx[i];
  int pos = atomicAdd(&cur[e], 1);
  int row = offs[e] + pos;
  rtok[row] = i >> 2;
  rw[row] = tw[i];
}

// ================= GEMM1: act = silu(x Wg) * (x Wu) =================
// BM=128, BN=32 (both mats), BK=64, 256 thr (4 waves, 2m x 2n).
// A [128][64] bf16 unpadded, XOR chunk-swizzle (conflict-free b128).
// B transposed [n][k] bf16, stride 72 (2-way, free). 1 barrier/step.
// No min-waves launch bound: let VGPRs grow so the pipeline stays live.
__global__ __launch_bounds__(256) void gemm1_kernel(const u16* __restrict__ xb,
                                                    const float* __restrict__ wgp,
                                                    const float* __restrict__ wup,
                                                    const int* __restrict__ offs,
                                                    const int* __restrict__ rtok,
                                                    u16* __restrict__ act) {
  int d = blockIdx.x;
  int e = d & 31;
  int nt = (d >> 5) % 24;          // 24 n-tiles of 32
  int mt = d / 768;                // 0..7 (128-row m-tiles)
  int off = offs[e], cnt = offs[e + 1] - off;
  int m0 = mt << 7;
  if (m0 >= cnt) return;
  int rows = cnt - m0; if (rows > 128) rows = 128;
  int baser = off + m0;
  int n0 = nt << 5;

  __shared__ __align__(16) u16 As[2][128 * 64];      // 32 KB
  __shared__ __align__(16) u16 Bs[2][2][32 * LDB];   // 18 KB

  int tid = threadIdx.x;
  int ln = tid & 63, wv = tid >> 6;
  int wm = wv >> 1, wn = wv & 1;
  int lhi = ln >> 4, llo = ln & 15;

  // ---- A staging: 2 thr/row, 64B each ----
  int ar = tid >> 1;
  int ah = tid & 1;
  int arow = ar < rows ? ar : rows - 1;
  const char* aSrc = (const char*)(xb + (long)rtok[baser + arow] * HDIM) + ah * 64;
  int wA[4];
#pragma unroll
  for (int j = 0; j < 4; j++) {
    int c = ah * 4 + j;
    wA[j] = ar * 128 + ((c ^ (ar & 7)) << 4);
  }

  // ---- B staging: mat = tid>>7; qk k-pair 0..31; g4 col-chunk 0..3 ----
  int mat = tid >> 7;
  int tt = tid & 127;
  int qk = tt & 31;
  int g4 = tt >> 5;
  const float* bSrc = (mat ? wup : wgp) + (long)e * (HDIM * IDIM) +
                      (long)(2 * qk) * IDIM + n0 + 4 * g4;

  // ---- read offsets (bytes) ----
  int rA[4][2];
#pragma unroll
  for (int mf = 0; mf < 4; mf++) {
    int r = wm * 64 + mf * 16 + llo;
#pragma unroll
    for (int kk = 0; kk < 2; kk++)
      rA[mf][kk] = r * 128 + ((((kk << 2) + lhi) ^ (r & 7)) << 4);
  }
  int rB0, rB1;
  {
    int c = wn * 16 + llo;
    rB0 = c * (LDB * 2) + lhi * 16;
    rB1 = rB0 + 64;
  }

  f32x4 accg[4], accu[4];
  f32x4 zz = {0.f, 0.f, 0.f, 0.f};
#pragma unroll
  for (int a = 0; a < 4; a++) { accg[a] = zz; accu[a] = zz; }

  u16x8 a_[4];
  float4 b_[4];

#define LD1(t)                                                        \
  {                                                                   \
    const char* p = aSrc + (long)(t) * 128;                           \
    a_[0] = *(const u16x8*)p;       a_[1] = *(const u16x8*)(p + 16);  \
    a_[2] = *(const u16x8*)(p + 32); a_[3] = *(const u16x8*)(p + 48); \
    const float* q = bSrc + (long)(t) * 64 * IDIM;                    \
    b_[0] = *(const float4*)q;        b_[1] = *(const float4*)(q + IDIM);      \
    b_[2] = *(const float4*)(q + 16); b_[3] = *(const float4*)(q + IDIM + 16); \
  }
#define ST1(buf)                                                      \
  {                                                                   \
    char* ab = (char*)As[buf];                                        \
    *(u16x8*)(ab + wA[0]) = a_[0]; *(u16x8*)(ab + wA[1]) = a_[1];     \
    *(u16x8*)(ab + wA[2]) = a_[2]; *(u16x8*)(ab + wA[3]) = a_[3];     \
    u16* w0 = &Bs[buf][mat][(4 * g4) * LDB + 2 * qk];                 \
    *(u32*)(w0 + 0 * LDB) = pk2(b_[0].x, b_[1].x);                    \
    *(u32*)(w0 + 1 * LDB) = pk2(b_[0].y, b_[1].y);                    \
    *(u32*)(w0 + 2 * LDB) = pk2(b_[0].z, b_[1].z);                    \
    *(u32*)(w0 + 3 * LDB) = pk2(b_[0].w, b_[1].w);                    \
    u16* w1 = &Bs[buf][mat][(16 + 4 * g4) * LDB + 2 * qk];            \
    *(u32*)(w1 + 0 * LDB) = pk2(b_[2].x, b_[3].x);                    \
    *(u32*)(w1 + 1 * LDB) = pk2(b_[2].y, b_[3].y);                    \
    *(u32*)(w1 + 2 * LDB) = pk2(b_[2].z, b_[3].z);                    \
    *(u32*)(w1 + 3 * LDB) = pk2(b_[2].w, b_[3].w);                    \
  }

  const int NS = HDIM / 64;  // 32
  LD1(0);
  ST1(0);
  __syncthreads();

  for (int t = 0; t < NS; ++t) {
    int cur = t & 1;
    if (t + 1 < NS) LD1(t + 1);
    {
      const char* Ab = (const char*)As[cur];
      const char* Bg = (const char*)Bs[cur][0];
      const char* Bu = (const char*)Bs[cur][1];
      s16x8 av[4][2];
#pragma unroll
      for (int mf = 0; mf < 4; mf++) {
        av[mf][0] = *(const s16x8*)(Ab + rA[mf][0]);
        av[mf][1] = *(const s16x8*)(Ab + rA[mf][1]);
      }
      s16x8 g0 = *(const s16x8*)(Bg + rB0);
      s16x8 g1 = *(const s16x8*)(Bg + rB1);
      s16x8 u0 = *(const s16x8*)(Bu + rB0);
      s16x8 u1 = *(const s16x8*)(Bu + rB1);
#pragma unroll
      for (int mf = 0; mf < 4; mf++)
        accg[mf] = __builtin_amdgcn_mfma_f32_16x16x32_bf16(av[mf][0], g0, accg[mf], 0, 0, 0);
#pragma unroll
      for (int mf = 0; mf < 4; mf++)
        accu[mf] = __builtin_amdgcn_mfma_f32_16x16x32_bf16(av[mf][0], u0, accu[mf], 0, 0, 0);
#pragma unroll
      for (int mf = 0; mf < 4; mf++)
        accg[mf] = __builtin_amdgcn_mfma_f32_16x16x32_bf16(av[mf][1], g1, accg[mf], 0, 0, 0);
#pragma unroll
      for (int mf = 0; mf < 4; mf++)
        accu[mf] = __builtin_amdgcn_mfma_f32_16x16x32_bf16(av[mf][1], u1, accu[mf], 0, 0, 0);
    }
    if (t + 1 < NS) ST1(cur ^ 1);
    __syncthreads();
  }

  // epilogue: silu(g)*u -> bf16 act
  int rb = wm * 64 + lhi * 4;
  int cb = n0 + wn * 16 + llo;
#pragma unroll
  for (int mf = 0; mf < 4; mf++) {
#pragma unroll
    for (int r4 = 0; r4 < 4; r4++) {
      int rl = rb + mf * 16 + r4;
      if (rl < rows) {
        float g = accg[mf][r4], u = accu[mf][r4];
        float av = g / (1.f + __expf(-g)) * u;
        act[(long)(baser + rl) * IDIM + cb] = f2bf(av);
      }
    }
  }
#undef LD1
#undef ST1
}

// ================= GEMM2: out[tok] += w * (act Wd) =================
// BM=128, BN=64, BK=64, 256 thr (4 waves, 2m x 2n). Same template.
__global__ __launch_bounds__(256) void gemm2_kernel(const u16* __restrict__ act,
                                                    const float* __restrict__ wdp,
                                                    const int* __restrict__ offs,
                                                    const int* __restrict__ rtok,
                                                    const float* __restrict__ rw,
                                                    float* __restrict__ out) {
  int d = blockIdx.x;
  int e = d & 31;
  int nt = (d >> 5) & 31;          // 32 n-tiles of 64
  int mt = d >> 10;                // 0..7
  int off = offs[e], cnt = offs[e + 1] - off;
  int m0 = mt << 7;
  if (m0 >= cnt) return;
  int rows = cnt - m0; if (rows > 128) rows = 128;
  int baser = off + m0;
  int n0 = nt << 6;

  __shared__ __align__(16) u16 As[2][128 * 64];    // 32 KB
  __shared__ __align__(16) u16 Bs[2][64 * LDB];    // 18 KB

  int tid = threadIdx.x;
  int ln = tid & 63, wv = tid >> 6;
  int wm = wv >> 1, wn = wv & 1;
  int lhi = ln >> 4, llo = ln & 15;

  int ar = tid >> 1;
  int ah = tid & 1;
  int arow = ar < rows ? ar : rows - 1;
  const char* aSrc = (const char*)(act + (long)(baser + arow) * IDIM) + ah * 64;
  int wA[4];
#pragma unroll
  for (int j = 0; j < 4; j++) {
    int c = ah * 4 + j;
    wA[j] = ar * 128 + ((c ^ (ar & 7)) << 4);
  }

  int qk = tid & 31;
  int g4 = (tid >> 5) & 7;         // cols 4g4 and 32+4g4
  const float* bSrc = wdp + (long)e * (IDIM * HDIM) + (long)(2 * qk) * HDIM + n0 + 4 * g4;

  int rA[4][2];
#pragma unroll
  for (int mf = 0; mf < 4; mf++) {
    int r = wm * 64 + mf * 16 + llo;
#pragma unroll
    for (int kk = 0; kk < 2; kk++)
      rA[mf][kk] = r * 128 + ((((kk << 2) + lhi) ^ (r & 7)) << 4);
  }
  int rB[2][2];
#pragma unroll
  for (int nf = 0; nf < 2; nf++) {
    int c = wn * 32 + nf * 16 + llo;
    rB[nf][0] = c * (LDB * 2) + lhi * 16;
    rB[nf][1] = rB[nf][0] + 64;
  }

  f32x4 acc[4][2];
  f32x4 zz = {0.f, 0.f, 0.f, 0.f};
#pragma unroll
  for (int a = 0; a < 4; a++)
#pragma unroll
    for (int b = 0; b < 2; b++) acc[a][b] = zz;

  u16x8 a_[4];
  float4 b_[4];

#define LD2(t)                                                        \
  {                                                                   \
    const char* p = aSrc + (long)(t) * 128;                           \
    a_[0] = *(const u16x8*)p;       a_[1] = *(const u16x8*)(p + 16);  \
    a_[2] = *(const u16x8*)(p + 32); a_[3] = *(const u16x8*)(p + 48); \
    const float* q = bSrc + (long)(t) * 64 * HDIM;                    \
    b_[0] = *(const float4*)q;        b_[1] = *(const float4*)(q + HDIM);      \
    b_[2] = *(const float4*)(q + 32); b_[3] = *(const float4*)(q + HDIM + 32); \
  }
#define ST2(buf)                                                      \
  {                                                                   \
    char* ab = (char*)As[buf];                                        \
    *(u16x8*)(ab + wA[0]) = a_[0]; *(u16x8*)(ab + wA[1]) = a_[1];     \
    *(u16x8*)(ab + wA[2]) = a_[2]; *(u16x8*)(ab + wA[3]) = a_[3];     \
    u16* w0 = &Bs[buf][(4 * g4) * LDB + 2 * qk];                      \
    *(u32*)(w0 + 0 * LDB) = pk2(b_[0].x, b_[1].x);                    \
    *(u32*)(w0 + 1 * LDB) = pk2(b_[0].y, b_[1].y);                    \
    *(u32*)(w0 + 2 * LDB) = pk2(b_[0].z, b_[1].z);                    \
    *(u32*)(w0 + 3 * LDB) = pk2(b_[0].w, b_[1].w);                    \
    u16* w1 = &Bs[buf][(32 + 4 * g4) * LDB + 2 * qk];                 \
    *(u32*)(w1 + 0 * LDB) = pk2(b_[2].x, b_[3].x);                    \
    *(u32*)(w1 + 1 * LDB) = pk2(b_[2].y, b_[3].y);                    \
    *(u32*)(w1 + 2 * LDB) = pk2(b_[2].z, b_[3].z);                    \
    *(u32*)(w1 + 3 * LDB) = pk2(b_[2].w, b_[3].w);                    \
  }

  const int NS = IDIM / 64;  // 12
  LD2(0);
  ST2(0);
  __syncthreads();

  for (int t = 0; t < NS; ++t) {
    int cur = t & 1;
    if (t + 1 < NS) LD2(t + 1);
    {
      const char* Ab = (const char*)As[cur];
      const char* Bb = (const char*)Bs[cur];
      s16x8 av[4][2];
#pragma unroll
      for (int mf = 0; mf < 4; mf++) {
        av[mf][0] = *(const s16x8*)(Ab + rA[mf][0]);
        av[mf][1] = *(const s16x8*)(Ab + rA[mf][1]);
      }
      s16x8 b00 = *(const s16x8*)(Bb + rB[0][0]);
      s16x8 b01 = *(const s16x8*)(Bb + rB[0][1]);
      s16x8 b10 = *(const s16x8*)(Bb + rB[1][0]);
      s16x8 b11 = *(const s16x8*)(Bb + rB[1][1]);
#pragma unroll
      for (int mf = 0; mf < 4; mf++)
        acc[mf][0] = __builtin_amdgcn_mfma_f32_16x16x32_bf16(av[mf][0], b00, acc[mf][0], 0, 0, 0);
#pragma unroll
      for (int mf = 0; mf < 4; mf++)
        acc[mf][1] = __builtin_amdgcn_mfma_f32_16x16x32_bf16(av[mf][0], b10, acc[mf][1], 0, 0, 0);
#pragma unroll
      for (int mf = 0; mf < 4; mf++)
        acc[mf][0] = __builtin_amdgcn_mfma_f32_16x16x32_bf16(av[mf][1], b01, acc[mf][0], 0, 0, 0);
#pragma unroll
      for (int mf = 0; mf < 4; mf++)
        acc[mf][1] = __builtin_amdgcn_mfma_f32_16x16x32_bf16(av[mf][1], b11, acc[mf][1], 0, 0, 0);
    }
    if (t + 1 < NS) ST2(cur ^ 1);
    __syncthreads();
  }

  // epilogue: scale by routing weight, atomic add into out
  int rb = wm * 64 + lhi * 4;
  int cb = n0 + wn * 32 + llo;
#pragma unroll
  for (int mf = 0; mf < 4; mf++) {
#pragma unroll
    for (int r4 = 0; r4 < 4; r4++) {
      int rl = rb + mf * 16 + r4;
      if (rl < rows) {
        int rr = baser + rl;
        float wt = rw[rr];
        long ob = (long)rtok[rr] * HDIM + cb;
        atomicAdd(&out[ob], acc[mf][0][r4] * wt);
        atomicAdd(&out[ob + 16], acc[mf][1][r4] * wt);
      }
    }
  }
#undef LD2
#undef ST2
}

extern "C" void kernel_launch(void* const* d_in, const int* in_sizes, int n_in,
                              void* d_out, int out_size, void* d_ws, size_t ws_size,
                              hipStream_t stream) {
  const float* x = (const float*)d_in[0];
  const float* gw = (const float*)d_in[1];
  const float* wgate = (const float*)d_in[2];
  const float* wup = (const float*)d_in[3];
  const float* wdown = (const float*)d_in[4];
  float* out = (float*)d_out;

  char* ws = (char*)d_ws;
  u16* xb = (u16*)(ws + WS_XB);
  u16* act = (u16*)(ws + WS_ACT);
  int* tidx = (int*)(ws + WS_TIDX);
  float* tw = (float*)(ws + WS_TW);
  int* cnt = (int*)(ws + WS_CNT);
  int* offs = (int*)(ws + WS_OFFS);
  int* cur = (int*)(ws + WS_CUR);
  int* rtok = (int*)(ws + WS_RTOK);
  float* rw = (float*)(ws + WS_RW);

  hipMemsetAsync(cnt, 0, 128, stream);
  hipMemsetAsync(d_out, 0, (size_t)out_size * sizeof(float), stream);

  hipLaunchKernelGGL(cvt_x_kernel, dim3(TTOK * HDIM / (256 * 8)), dim3(256), 0, stream, x, xb);
  hipLaunchKernelGGL(router_kernel, dim3(TTOK), dim3(256), 0, stream, x, gw, tidx, tw, cnt);
  hipLaunchKernelGGL(scan_kernel, dim3(1), dim3(64), 0, stream, cnt, offs, cur);
  hipLaunchKernelGGL(scatter_kernel, dim3(TTOK * KTOP / 256), dim3(256), 0, stream, tidx, tw, offs, cur, rtok, rw);
  hipLaunchKernelGGL(gemm1_kernel, dim3(32 * 24 * 8), dim3(256), 0, stream, xb, wgate, wup, offs, rtok, act);
  hipLaunchKernelGGL(gemm2_kernel, dim3(32 * 32 * 8), dim3(256), 0, stream, act, wdown, offs, rtok, rw, out);
}

// Round 7
// 447.868 us; speedup vs baseline: 1.6978x; 1.3068x over previous
//
#include <hip/hip_runtime.h>
#include <hip/hip_bf16.h>
#include <math.h>

typedef unsigned short u16;
typedef unsigned int u32;
typedef unsigned long long u64;
typedef short s16x8 __attribute__((ext_vector_type(8)));
typedef u32 u32x2 __attribute__((ext_vector_type(2)));
typedef u32 u32x4 __attribute__((ext_vector_type(4)));
typedef float f32x4 __attribute__((ext_vector_type(4)));

// Problem constants
#define TTOK 2048
#define HDIM 2048
#define ENUM 32
#define IDIM 768
#define KTOP 4

// Workspace layout (bytes)
#define WS_XB   0L
#define WS_ACT  8388608L
#define WS_TIDX 20971520L
#define WS_TW   (WS_TIDX + 32768L)
#define WS_CNT  (WS_TW + 32768L)
#define WS_OFFS (WS_CNT + 128L)
#define WS_CUR  (WS_OFFS + 256L)
#define WS_RTOK (WS_CUR + 128L)
#define WS_RW   (WS_RTOK + 32768L)

#define LDBW 20   // B LDS row stride in dwords (16 data k-pairs + 4 pad)

__device__ __forceinline__ u16 f2bf(float f) {
  unsigned u = __builtin_bit_cast(unsigned, f);
  unsigned r = (u + 0x7fffu + ((u >> 16) & 1u)) >> 16;
  return (u16)r;
}

__device__ __forceinline__ u32 cvtpk(float lo, float hi) {
  u32 r;
  asm("v_cvt_pk_bf16_f32 %0, %1, %2" : "=v"(r) : "v"(lo), "v"(hi));
  return r;
}

// async global->LDS, 16B per lane, LDS dest = uniform base + lane*16 (linear)
__device__ __forceinline__ void gll16(const void* g, void* l) {
  u32 loff = __builtin_amdgcn_readfirstlane((u32)(u64)l);
  __builtin_amdgcn_global_load_lds(
      (const __attribute__((address_space(1))) u32*)(u64)g,
      (__attribute__((address_space(3))) u32*)loff, 16, 0, 0);
}

// B fragment: two ds_read_b64 from swizzled transposed layout
__device__ __forceinline__ s16x8 bfrag(const u32* B, int d0, int d1) {
  u32x2 lo = *(const u32x2*)(B + d0);
  u32x2 hi = *(const u32x2*)(B + d1);
  u32x4 v = {lo.x, lo.y, hi.x, hi.y};
  return __builtin_bit_cast(s16x8, v);
}

// ---------------- router (also emits xb = bf16(x)) ----------------
__global__ __launch_bounds__(256) void router_kernel(const float* __restrict__ x,
                                                     const float* __restrict__ gw,
                                                     u16* __restrict__ xb,
                                                     int* __restrict__ tidx,
                                                     float* __restrict__ tw,
                                                     int* __restrict__ counts) {
  __shared__ float xs[HDIM];
  __shared__ float part[256];
  __shared__ float lg[ENUM];
  int t = blockIdx.x;
  const float4* xr = (const float4*)(x + (long)t * HDIM);
  float4* xs4 = (float4*)xs;
  for (int i = threadIdx.x; i < HDIM / 4; i += 256) xs4[i] = xr[i];
  __syncthreads();
  // emit bf16 row
  {
    int i0 = threadIdx.x * 8;
    uint4 o;
    o.x = cvtpk(xs[i0], xs[i0 + 1]);
    o.y = cvtpk(xs[i0 + 2], xs[i0 + 3]);
    o.z = cvtpk(xs[i0 + 4], xs[i0 + 5]);
    o.w = cvtpk(xs[i0 + 6], xs[i0 + 7]);
    *(uint4*)(xb + (long)t * HDIM + i0) = o;
  }
  int e = threadIdx.x >> 3, ch = threadIdx.x & 7;
  const float4* gp = (const float4*)(gw + (long)e * HDIM + ch * 256);
  const float4* xp = (const float4*)(xs + ch * 256);
  float s = 0.f;
#pragma unroll 8
  for (int c = 0; c < 64; c++) {
    float4 gv = gp[c], xv = xp[c];
    s += gv.x * xv.x + gv.y * xv.y + gv.z * xv.z + gv.w * xv.w;
  }
  part[threadIdx.x] = s;
  __syncthreads();
  if (threadIdx.x < 32) {
    float v = 0.f;
#pragma unroll
    for (int j = 0; j < 8; j++) v += part[threadIdx.x * 8 + j];
    lg[threadIdx.x] = v;
  }
  __syncthreads();
  if (threadIdx.x == 0) {
    int sel[KTOP]; float sv[KTOP];
    unsigned mask = 0;
    for (int k = 0; k < KTOP; k++) {
      float best = -INFINITY; int bi = 0;
      for (int j = 0; j < ENUM; j++)
        if (!((mask >> j) & 1u) && lg[j] > best) { best = lg[j]; bi = j; }
      mask |= 1u << bi; sel[k] = bi; sv[k] = best;
    }
    float m = sv[0], den = 0.f, ex[KTOP];
    for (int k = 0; k < KTOP; k++) { ex[k] = expf(sv[k] - m); den += ex[k]; }
    for (int k = 0; k < KTOP; k++) {
      tidx[t * KTOP + k] = sel[k];
      tw[t * KTOP + k] = ex[k] / den;
      atomicAdd(&counts[sel[k]], 1);
    }
  }
}

// ---------------- scan ----------------
__global__ void scan_kernel(const int* __restrict__ counts, int* __restrict__ offs,
                            int* __restrict__ cur) {
  if (threadIdx.x == 0) {
    int a = 0;
    for (int e = 0; e < ENUM; e++) { offs[e] = a; a += counts[e]; }
    offs[ENUM] = a;
  }
  if (threadIdx.x < ENUM) cur[threadIdx.x] = 0;
}

// ---------------- scatter ----------------
__global__ __launch_bounds__(256) void scatter_kernel(const int* __restrict__ tidx,
                                                      const float* __restrict__ tw,
                                                      const int* __restrict__ offs,
                                                      int* __restrict__ cur,
                                                      int* __restrict__ rtok,
                                                      float* __restrict__ rw) {
  int i = blockIdx.x * 256 + threadIdx.x;
  int e = tidx[i];
  int pos = atomicAdd(&cur[e], 1);
  int row = offs[e] + pos;
  rtok[row] = i >> 2;
  rw[row] = tw[i];
}

// ================= GEMM1: act = silu(x Wg) * (x Wu) =================
// BM=256, BN=64, BK=32, 512 thr (8 waves 4m x 2n).
// A: bf16 via global_load_lds, linear LDS, source-side chunk-XOR swizzle.
// B: f32 coalesced k-pair loads -> cvt_pk -> transposed [n][20dw] LDS,
//    dword-XOR swizzle, b64 fragment reads.
__global__ __launch_bounds__(512) void gemm1_kernel(const u16* __restrict__ xb,
                                                    const float* __restrict__ wgp,
                                                    const float* __restrict__ wup,
                                                    const int* __restrict__ offs,
                                                    const int* __restrict__ rtok,
                                                    u16* __restrict__ act) {
  int d = blockIdx.x;
  int e = d & 31;
  int nt = (d >> 5) % 12;
  int mt = d / 384;
  int off = offs[e], cnt = offs[e + 1] - off;
  int m0 = mt << 8;
  if (m0 >= cnt) return;
  int rows = cnt - m0; if (rows > 256) rows = 256;
  int baser = off + m0;
  int n0 = nt << 6;

  __shared__ __align__(16) u16 As[2][256 * 32];       // 32 KB
  __shared__ __align__(16) u32 Bs[2][2][64 * LDBW];   // 20 KB

  int tid = threadIdx.x;
  int ln = tid & 63, w = tid >> 6;
  int wm = w >> 1, wn = w & 1;
  int lhi = ln >> 4, llo = ln & 15;

  // ---- A gll setup: 2 instrs per wave, lane covers (row, 16B chunk) ----
  const u16* gA[2];
  int ldsA[2];
#pragma unroll
  for (int j = 0; j < 2; j++) {
    int idx = w * 2 + j;
    int r = idx * 16 + (ln >> 2);
    int c = ln & 3;
    int csrc = c ^ ((r >> 1) & 3);
    int rr = r < rows ? r : rows - 1;
    gA[j] = xb + (long)rtok[baser + rr] * HDIM + csrc * 8;
    ldsA[j] = idx * 1024;
  }

  // ---- B staging: thread -> (mat, n-quad a, k-pair kk) ----
  int mat = tid >> 8;
  int t2 = tid & 255;
  int a = t2 & 15;
  int kk = t2 >> 4;
  const float* gB = (mat ? wup : wgp) + (long)e * ((long)HDIM * IDIM) +
                    (long)(2 * kk) * IDIM + n0 + 4 * a;
  int fB = 2 * (a & 7);
  int wOff[4];
#pragma unroll
  for (int j = 0; j < 4; j++) wOff[j] = (4 * a + j) * LDBW + (kk ^ fB);

  // ---- read offsets ----
  int offA[4];
#pragma unroll
  for (int mf = 0; mf < 4; mf++) {
    int r = wm * 64 + mf * 16 + llo;
    offA[mf] = r * 64 + ((lhi ^ ((r >> 1) & 3)) * 16);
  }
  int dB0[2], dB1[2];
#pragma unroll
  for (int nf = 0; nf < 2; nf++) {
    int n = wn * 32 + nf * 16 + llo;
    int f = 2 * ((n >> 2) & 7);
    dB0[nf] = n * LDBW + ((4 * lhi) ^ f);
    dB1[nf] = n * LDBW + (((4 * lhi) | 2) ^ f);
  }

  f32x4 accg[4][2], accu[4][2];
  f32x4 zz = {0.f, 0.f, 0.f, 0.f};
#pragma unroll
  for (int i = 0; i < 4; i++)
#pragma unroll
    for (int j = 0; j < 2; j++) { accg[i][j] = zz; accu[i][j] = zz; }

  float4 rB0, rB1;

  // prologue: stage step 0 into buf 0
  rB0 = *(const float4*)gB;
  rB1 = *(const float4*)(gB + IDIM);
  gll16(gA[0], (char*)As[0] + ldsA[0]);
  gll16(gA[1], (char*)As[0] + ldsA[1]);
  {
    u32* bb = &Bs[0][mat][0];
    bb[wOff[0]] = cvtpk(rB0.x, rB1.x);
    bb[wOff[1]] = cvtpk(rB0.y, rB1.y);
    bb[wOff[2]] = cvtpk(rB0.z, rB1.z);
    bb[wOff[3]] = cvtpk(rB0.w, rB1.w);
  }
  __syncthreads();

  const int NS = HDIM / 32;  // 64
  int buf = 0;
  for (int t = 0; t < NS; ++t) {
    if (t + 1 < NS) {
      const float* p = gB + (long)(t + 1) * 32 * IDIM;
      rB0 = *(const float4*)p;
      rB1 = *(const float4*)(p + IDIM);
      gll16(gA[0] + (t + 1) * 32, (char*)As[buf ^ 1] + ldsA[0]);
      gll16(gA[1] + (t + 1) * 32, (char*)As[buf ^ 1] + ldsA[1]);
    }
    __builtin_amdgcn_sched_barrier(0);
    {
      const char* Ab = (const char*)As[buf];
      const u32* Bg = &Bs[buf][0][0];
      const u32* Bu = &Bs[buf][1][0];
      s16x8 av[4];
#pragma unroll
      for (int mf = 0; mf < 4; mf++) av[mf] = *(const s16x8*)(Ab + offA[mf]);
#pragma unroll
      for (int nf = 0; nf < 2; nf++) {
        s16x8 bg = bfrag(Bg, dB0[nf], dB1[nf]);
        s16x8 bu = bfrag(Bu, dB0[nf], dB1[nf]);
#pragma unroll
        for (int mf = 0; mf < 4; mf++) {
          accg[mf][nf] = __builtin_amdgcn_mfma_f32_16x16x32_bf16(av[mf], bg, accg[mf][nf], 0, 0, 0);
          accu[mf][nf] = __builtin_amdgcn_mfma_f32_16x16x32_bf16(av[mf], bu, accu[mf][nf], 0, 0, 0);
        }
      }
    }
    if (t + 1 < NS) {
      u32* bb = &Bs[buf ^ 1][mat][0];
      bb[wOff[0]] = cvtpk(rB0.x, rB1.x);
      bb[wOff[1]] = cvtpk(rB0.y, rB1.y);
      bb[wOff[2]] = cvtpk(rB0.z, rB1.z);
      bb[wOff[3]] = cvtpk(rB0.w, rB1.w);
    }
    __syncthreads();
    buf ^= 1;
  }

  // epilogue: silu(g)*u -> bf16 act
  int rb = wm * 64 + lhi * 4;
  int cb = n0 + wn * 32 + llo;
#pragma unroll
  for (int mf = 0; mf < 4; mf++) {
#pragma unroll
    for (int r4 = 0; r4 < 4; r4++) {
      int rl = rb + mf * 16 + r4;
      if (rl < rows) {
        long rowb = (long)(baser + rl) * IDIM;
#pragma unroll
        for (int nf = 0; nf < 2; nf++) {
          float g = accg[mf][nf][r4], u = accu[mf][nf][r4];
          float av = g / (1.f + __expf(-g)) * u;
          act[rowb + cb + nf * 16] = f2bf(av);
        }
      }
    }
  }
}

// ================= GEMM2: out[tok] += w * (act Wd) =================
// BM=256, BN=64, BK=32, 512 thr (8 waves 4m x 2n). Same template, one mat.
__global__ __launch_bounds__(512) void gemm2_kernel(const u16* __restrict__ act,
                                                    const float* __restrict__ wdp,
                                                    const int* __restrict__ offs,
                                                    const int* __restrict__ rtok,
                                                    const float* __restrict__ rw,
                                                    float* __restrict__ out) {
  int d = blockIdx.x;
  int e = d & 31;
  int nt = (d >> 5) & 31;
  int mt = d >> 10;
  int off = offs[e], cnt = offs[e + 1] - off;
  int m0 = mt << 8;
  if (m0 >= cnt) return;
  int rows = cnt - m0; if (rows > 256) rows = 256;
  int baser = off + m0;
  int n0 = nt << 6;

  __shared__ __align__(16) u16 As[2][256 * 32];    // 32 KB
  __shared__ __align__(16) u32 Bs[2][64 * LDBW];   // 10 KB

  int tid = threadIdx.x;
  int ln = tid & 63, w = tid >> 6;
  int wm = w >> 1, wn = w & 1;
  int lhi = ln >> 4, llo = ln & 15;

  const u16* gA[2];
  int ldsA[2];
#pragma unroll
  for (int j = 0; j < 2; j++) {
    int idx = w * 2 + j;
    int r = idx * 16 + (ln >> 2);
    int c = ln & 3;
    int csrc = c ^ ((r >> 1) & 3);
    int rr = r < rows ? r : rows - 1;
    gA[j] = act + (long)(baser + rr) * IDIM + csrc * 8;
    ldsA[j] = idx * 1024;
  }

  int isB = (tid < 256);
  int a = tid & 15;
  int kk = (tid >> 4) & 15;
  const float* gB = wdp + (long)e * ((long)IDIM * HDIM) +
                    (long)(2 * kk) * HDIM + n0 + 4 * a;
  int fB = 2 * (a & 7);
  int wOff[4];
#pragma unroll
  for (int j = 0; j < 4; j++) wOff[j] = (4 * a + j) * LDBW + (kk ^ fB);

  int offA[4];
#pragma unroll
  for (int mf = 0; mf < 4; mf++) {
    int r = wm * 64 + mf * 16 + llo;
    offA[mf] = r * 64 + ((lhi ^ ((r >> 1) & 3)) * 16);
  }
  int dB0[2], dB1[2];
#pragma unroll
  for (int nf = 0; nf < 2; nf++) {
    int n = wn * 32 + nf * 16 + llo;
    int f = 2 * ((n >> 2) & 7);
    dB0[nf] = n * LDBW + ((4 * lhi) ^ f);
    dB1[nf] = n * LDBW + (((4 * lhi) | 2) ^ f);
  }

  f32x4 acc[4][2];
  f32x4 zz = {0.f, 0.f, 0.f, 0.f};
#pragma unroll
  for (int i = 0; i < 4; i++)
#pragma unroll
    for (int j = 0; j < 2; j++) acc[i][j] = zz;

  float4 rB0, rB1;

  if (isB) {
    rB0 = *(const float4*)gB;
    rB1 = *(const float4*)(gB + HDIM);
  }
  gll16(gA[0], (char*)As[0] + ldsA[0]);
  gll16(gA[1], (char*)As[0] + ldsA[1]);
  if (isB) {
    u32* bb = &Bs[0][0];
    bb[wOff[0]] = cvtpk(rB0.x, rB1.x);
    bb[wOff[1]] = cvtpk(rB0.y, rB1.y);
    bb[wOff[2]] = cvtpk(rB0.z, rB1.z);
    bb[wOff[3]] = cvtpk(rB0.w, rB1.w);
  }
  __syncthreads();

  const int NS = IDIM / 32;  // 24
  int buf = 0;
  for (int t = 0; t < NS; ++t) {
    if (t + 1 < NS) {
      if (isB) {
        const float* p = gB + (long)(t + 1) * 32 * HDIM;
        rB0 = *(const float4*)p;
        rB1 = *(const float4*)(p + HDIM);
      }
      gll16(gA[0] + (t + 1) * 32, (char*)As[buf ^ 1] + ldsA[0]);
      gll16(gA[1] + (t + 1) * 32, (char*)As[buf ^ 1] + ldsA[1]);
    }
    __builtin_amdgcn_sched_barrier(0);
    {
      const char* Ab = (const char*)As[buf];
      const u32* Bb = &Bs[buf][0];
      s16x8 av[4];
#pragma unroll
      for (int mf = 0; mf < 4; mf++) av[mf] = *(const s16x8*)(Ab + offA[mf]);
#pragma unroll
      for (int nf = 0; nf < 2; nf++) {
        s16x8 bv = bfrag(Bb, dB0[nf], dB1[nf]);
#pragma unroll
        for (int mf = 0; mf < 4; mf++)
          acc[mf][nf] = __builtin_amdgcn_mfma_f32_16x16x32_bf16(av[mf], bv, acc[mf][nf], 0, 0, 0);
      }
    }
    if (t + 1 < NS && isB) {
      u32* bb = &Bs[buf ^ 1][0];
      bb[wOff[0]] = cvtpk(rB0.x, rB1.x);
      bb[wOff[1]] = cvtpk(rB0.y, rB1.y);
      bb[wOff[2]] = cvtpk(rB0.z, rB1.z);
      bb[wOff[3]] = cvtpk(rB0.w, rB1.w);
    }
    __syncthreads();
    buf ^= 1;
  }

  // epilogue: scale by routing weight, atomic add into out
  int rb = wm * 64 + lhi * 4;
  int cb = n0 + wn * 32 + llo;
#pragma unroll
  for (int mf = 0; mf < 4; mf++) {
#pragma unroll
    for (int r4 = 0; r4 < 4; r4++) {
      int rl = rb + mf * 16 + r4;
      if (rl < rows) {
        int rr = baser + rl;
        float wt = rw[rr];
        long ob = (long)rtok[rr] * HDIM + cb;
        atomicAdd(&out[ob], acc[mf][0][r4] * wt);
        atomicAdd(&out[ob + 16], acc[mf][1][r4] * wt);
      }
    }
  }
}

extern "C" void kernel_launch(void* const* d_in, const int* in_sizes, int n_in,
                              void* d_out, int out_size, void* d_ws, size_t ws_size,
                              hipStream_t stream) {
  const float* x = (const float*)d_in[0];
  const float* gw = (const float*)d_in[1];
  const float* wgate = (const float*)d_in[2];
  const float* wup = (const float*)d_in[3];
  const float* wdown = (const float*)d_in[4];
  float* out = (float*)d_out;

  char* ws = (char*)d_ws;
  u16* xb = (u16*)(ws + WS_XB);
  u16* act = (u16*)(ws + WS_ACT);
  int* tidx = (int*)(ws + WS_TIDX);
  float* tw = (float*)(ws + WS_TW);
  int* cnt = (int*)(ws + WS_CNT);
  int* offs = (int*)(ws + WS_OFFS);
  int* cur = (int*)(ws + WS_CUR);
  int* rtok = (int*)(ws + WS_RTOK);
  float* rw = (float*)(ws + WS_RW);

  hipMemsetAsync(cnt, 0, 128, stream);
  hipMemsetAsync(d_out, 0, (size_t)out_size * sizeof(float), stream);

  hipLaunchKernelGGL(router_kernel, dim3(TTOK), dim3(256), 0, stream, x, gw, xb, tidx, tw, cnt);
  hipLaunchKernelGGL(scan_kernel, dim3(1), dim3(64), 0, stream, cnt, offs, cur);
  hipLaunchKernelGGL(scatter_kernel, dim3(TTOK * KTOP / 256), dim3(256), 0, stream, tidx, tw, offs, cur, rtok, rw);
  hipLaunchKernelGGL(gemm1_kernel, dim3(32 * 12 * 8), dim3(512), 0, stream, xb, wgate, wup, offs, rtok, act);
  hipLaunchKernelGGL(gemm2_kernel, dim3(32 * 32 * 8), dim3(512), 0, stream, act, wdown, offs, rtok, rw, out);
}

// Round 8
// 444.231 us; speedup vs baseline: 1.7117x; 1.0082x over previous
//
#include <hip/hip_runtime.h>
#include <hip/hip_bf16.h>
#include <math.h>

typedef unsigned short u16;
typedef unsigned int u32;
typedef unsigned long long u64;
typedef short s16x8 __attribute__((ext_vector_type(8)));
typedef u16 u16x8 __attribute__((ext_vector_type(8)));
typedef u32 u32x2 __attribute__((ext_vector_type(2)));
typedef u32 u32x4 __attribute__((ext_vector_type(4)));
typedef float f32x4 __attribute__((ext_vector_type(4)));

// Problem constants
#define TTOK 2048
#define HDIM 2048
#define ENUM 32
#define IDIM 768
#define KTOP 4

// Workspace layout (bytes)
#define WS_XB   0L                          // 8 MB bf16 x
#define WS_ACT  8388608L                    // 12.6 MB bf16 act
#define WS_TIDX 20971520L
#define WS_TW   (WS_TIDX + 32768L)
#define WS_CNT  (WS_TW + 32768L)
#define WS_OFFS (WS_CNT + 128L)
#define WS_CUR  (WS_OFFS + 256L)
#define WS_RTOK (WS_CUR + 128L)
#define WS_RW   (WS_RTOK + 32768L)
#define WS_RMAP (WS_RW + 32768L)            // int[8192] (tok,slot) -> row
#define WS_EO   25165824L                   // 32 MB bf16 expert rows [8192][2048]
#define WS_NEED (WS_EO + 33554432L)

#define LDBW 20   // B LDS row stride in dwords

__device__ __forceinline__ u16 f2bf(float f) {
  unsigned u = __builtin_bit_cast(unsigned, f);
  unsigned r = (u + 0x7fffu + ((u >> 16) & 1u)) >> 16;
  return (u16)r;
}

__device__ __forceinline__ u32 cvtpk(float lo, float hi) {
  u32 r;
  asm("v_cvt_pk_bf16_f32 %0, %1, %2" : "=v"(r) : "v"(lo), "v"(hi));
  return r;
}

__device__ __forceinline__ void gll16(const void* g, void* l) {
  u32 loff = __builtin_amdgcn_readfirstlane((u32)(u64)l);
  __builtin_amdgcn_global_load_lds(
      (const __attribute__((address_space(1))) u32*)(u64)g,
      (__attribute__((address_space(3))) u32*)loff, 16, 0, 0);
}

__device__ __forceinline__ s16x8 bfrag(const u32* B, int d0, int d1) {
  u32x2 lo = *(const u32x2*)(B + d0);
  u32x2 hi = *(const u32x2*)(B + d1);
  u32x4 v = {lo.x, lo.y, hi.x, hi.y};
  return __builtin_bit_cast(s16x8, v);
}

#define WAIT_VM(N)                                            \
  do {                                                        \
    asm volatile("s_waitcnt vmcnt(" #N ")");                  \
    __builtin_amdgcn_sched_barrier(0);                        \
  } while (0)
#define BARRIER()                                             \
  do {                                                        \
    asm volatile("s_waitcnt lgkmcnt(0)");                     \
    __builtin_amdgcn_sched_barrier(0);                        \
    __builtin_amdgcn_s_barrier();                             \
    __builtin_amdgcn_sched_barrier(0);                        \
  } while (0)

// ---------------- router (also emits xb = bf16(x)) ----------------
__global__ __launch_bounds__(256) void router_kernel(const float* __restrict__ x,
                                                     const float* __restrict__ gw,
                                                     u16* __restrict__ xb,
                                                     int* __restrict__ tidx,
                                                     float* __restrict__ tw,
                                                     int* __restrict__ counts) {
  __shared__ float xs[HDIM];
  __shared__ float part[256];
  __shared__ float lg[ENUM];
  int t = blockIdx.x;
  const float4* xr = (const float4*)(x + (long)t * HDIM);
  float4* xs4 = (float4*)xs;
  for (int i = threadIdx.x; i < HDIM / 4; i += 256) xs4[i] = xr[i];
  __syncthreads();
  {
    int i0 = threadIdx.x * 8;
    uint4 o;
    o.x = cvtpk(xs[i0], xs[i0 + 1]);
    o.y = cvtpk(xs[i0 + 2], xs[i0 + 3]);
    o.z = cvtpk(xs[i0 + 4], xs[i0 + 5]);
    o.w = cvtpk(xs[i0 + 6], xs[i0 + 7]);
    *(uint4*)(xb + (long)t * HDIM + i0) = o;
  }
  int e = threadIdx.x >> 3, ch = threadIdx.x & 7;
  const float4* gp = (const float4*)(gw + (long)e * HDIM + ch * 256);
  const float4* xp = (const float4*)(xs + ch * 256);
  float s = 0.f;
#pragma unroll 8
  for (int c = 0; c < 64; c++) {
    float4 gv = gp[c], xv = xp[c];
    s += gv.x * xv.x + gv.y * xv.y + gv.z * xv.z + gv.w * xv.w;
  }
  part[threadIdx.x] = s;
  __syncthreads();
  if (threadIdx.x < 32) {
    float v = 0.f;
#pragma unroll
    for (int j = 0; j < 8; j++) v += part[threadIdx.x * 8 + j];
    lg[threadIdx.x] = v;
  }
  __syncthreads();
  if (threadIdx.x == 0) {
    int sel[KTOP]; float sv[KTOP];
    unsigned mask = 0;
    for (int k = 0; k < KTOP; k++) {
      float best = -INFINITY; int bi = 0;
      for (int j = 0; j < ENUM; j++)
        if (!((mask >> j) & 1u) && lg[j] > best) { best = lg[j]; bi = j; }
      mask |= 1u << bi; sel[k] = bi; sv[k] = best;
    }
    float m = sv[0], den = 0.f, ex[KTOP];
    for (int k = 0; k < KTOP; k++) { ex[k] = expf(sv[k] - m); den += ex[k]; }
    for (int k = 0; k < KTOP; k++) {
      tidx[t * KTOP + k] = sel[k];
      tw[t * KTOP + k] = ex[k] / den;
      atomicAdd(&counts[sel[k]], 1);
    }
  }
}

// ---------------- scan ----------------
__global__ void scan_kernel(const int* __restrict__ counts, int* __restrict__ offs,
                            int* __restrict__ cur) {
  if (threadIdx.x == 0) {
    int a = 0;
    for (int e = 0; e < ENUM; e++) { offs[e] = a; a += counts[e]; }
    offs[ENUM] = a;
  }
  if (threadIdx.x < ENUM) cur[threadIdx.x] = 0;
}

// ---------------- scatter ----------------
__global__ __launch_bounds__(256) void scatter_kernel(const int* __restrict__ tidx,
                                                      const float* __restrict__ tw,
                                                      const int* __restrict__ offs,
                                                      int* __restrict__ cur,
                                                      int* __restrict__ rtok,
                                                      float* __restrict__ rw,
                                                      int* __restrict__ rowmap) {
  int i = blockIdx.x * 256 + threadIdx.x;
  int e = tidx[i];
  int pos = atomicAdd(&cur[e], 1);
  int row = offs[e] + pos;
  rtok[row] = i >> 2;
  rw[row] = tw[i];
  rowmap[i] = row;
}

// ================= GEMM1: act = silu(x Wg) * (x Wu) =================
// BM=256, BN=64, BK=32, 512 thr (8 waves 4m x 2n).
// Counted-vmcnt pipeline: A via gll 2 steps ahead (3 LDS bufs),
// B f32 loads 2 steps ahead (reg ping-pong), raw barrier, vmcnt(4).
__global__ __launch_bounds__(512) void gemm1_kernel(const u16* __restrict__ xb,
                                                    const float* __restrict__ wgp,
                                                    const float* __restrict__ wup,
                                                    const int* __restrict__ offs,
                                                    const int* __restrict__ rtok,
                                                    u16* __restrict__ act) {
  int d = blockIdx.x;
  int e = d & 31;
  int nt = (d >> 5) % 12;
  int mt = d / 384;
  int off = offs[e], cnt = offs[e + 1] - off;
  int m0 = mt << 8;
  if (m0 >= cnt) return;
  int rows = cnt - m0; if (rows > 256) rows = 256;
  int baser = off + m0;
  int n0 = nt << 6;

  __shared__ __align__(16) u16 As[3][256 * 32];       // 48 KB
  __shared__ __align__(16) u32 Bs[2][2][64 * LDBW];   // 20 KB

  int tid = threadIdx.x;
  int ln = tid & 63, w = tid >> 6;
  int wm = w >> 1, wn = w & 1;
  int lhi = ln >> 4, llo = ln & 15;

  // A gll: 2 instrs/wave; lane -> (row, 16B chunk), source-side XOR swizzle
  const u16* gA[2];
  int ldsA[2];
#pragma unroll
  for (int j = 0; j < 2; j++) {
    int idx = w * 2 + j;
    int r = idx * 16 + (ln >> 2);
    int c = ln & 3;
    int csrc = c ^ ((r >> 1) & 3);
    int rr = r < rows ? r : rows - 1;
    gA[j] = xb + (long)rtok[baser + rr] * HDIM + csrc * 8;
    ldsA[j] = idx * 1024;
  }

  // B staging: thread -> (mat, n-quad a, k-pair kk)
  int mat = tid >> 8;
  int t2 = tid & 255;
  int a = t2 & 15;
  int kk = t2 >> 4;
  const float* gB = (mat ? wup : wgp) + (long)e * ((long)HDIM * IDIM) +
                    (long)(2 * kk) * IDIM + n0 + 4 * a;
  int fB = 2 * (a & 7);
  int wOff[4];
#pragma unroll
  for (int j = 0; j < 4; j++) wOff[j] = (4 * a + j) * LDBW + (kk ^ fB);

  int offA[4];
#pragma unroll
  for (int mf = 0; mf < 4; mf++) {
    int r = wm * 64 + mf * 16 + llo;
    offA[mf] = r * 64 + ((lhi ^ ((r >> 1) & 3)) * 16);
  }
  int dB0[2], dB1[2];
#pragma unroll
  for (int nf = 0; nf < 2; nf++) {
    int n = wn * 32 + nf * 16 + llo;
    int f = 2 * ((n >> 2) & 7);
    dB0[nf] = n * LDBW + ((4 * lhi) ^ f);
    dB1[nf] = n * LDBW + (((4 * lhi) | 2) ^ f);
  }

  f32x4 accg[4][2], accu[4][2];
  f32x4 zz = {0.f, 0.f, 0.f, 0.f};
#pragma unroll
  for (int i = 0; i < 4; i++)
#pragma unroll
    for (int j = 0; j < 2; j++) { accg[i][j] = zz; accu[i][j] = zz; }

  float4 rbA0, rbA1, rbB0, rbB1;

#define GLLA(pDst, tt)                                                \
  { gll16(gA[0] + (tt) * 32, (char*)(pDst) + ldsA[0]);                \
    gll16(gA[1] + (tt) * 32, (char*)(pDst) + ldsA[1]); }
#define LDB1(r0, r1, tt)                                              \
  { const float* p = gB + (long)(tt) * 32 * IDIM;                     \
    r0 = *(const float4*)p; r1 = *(const float4*)(p + IDIM); }
#define STB1(dstBs, r0, r1)                                           \
  { u32* bb = &(dstBs)[mat][0];                                       \
    bb[wOff[0]] = cvtpk(r0.x, r1.x);                                  \
    bb[wOff[1]] = cvtpk(r0.y, r1.y);                                  \
    bb[wOff[2]] = cvtpk(r0.z, r1.z);                                  \
    bb[wOff[3]] = cvtpk(r0.w, r1.w); }
#define COMP1(pA, bsel)                                               \
  {                                                                   \
    const char* Ab = (const char*)(pA);                               \
    const u32* Bg = &Bs[bsel][0][0];                                  \
    const u32* Bu = &Bs[bsel][1][0];                                  \
    s16x8 av[4];                                                      \
    _Pragma("unroll")                                                 \
    for (int mf = 0; mf < 4; mf++) av[mf] = *(const s16x8*)(Ab + offA[mf]); \
    _Pragma("unroll")                                                 \
    for (int nf = 0; nf < 2; nf++) {                                  \
      s16x8 bg = bfrag(Bg, dB0[nf], dB1[nf]);                         \
      s16x8 bu = bfrag(Bu, dB0[nf], dB1[nf]);                         \
      _Pragma("unroll")                                               \
      for (int mf = 0; mf < 4; mf++) {                                \
        accg[mf][nf] = __builtin_amdgcn_mfma_f32_16x16x32_bf16(av[mf], bg, accg[mf][nf], 0, 0, 0); \
        accu[mf][nf] = __builtin_amdgcn_mfma_f32_16x16x32_bf16(av[mf], bu, accu[mf][nf], 0, 0, 0); \
      }                                                               \
    }                                                                 \
  }

  const int NS = HDIM / 32;  // 64
  u16 *pC = As[0], *pN = As[1], *pD = As[2];

  // prologue
  GLLA(pC, 0); LDB1(rbA0, rbA1, 0);
  GLLA(pN, 1); LDB1(rbB0, rbB1, 1);
  __builtin_amdgcn_sched_barrier(0);
  STB1(Bs[0], rbA0, rbA1);
  WAIT_VM(4);
  BARRIER();

  for (int t = 0; t < NS; t += 2) {
    // even sub-step t
    if (t + 2 < NS) { GLLA(pD, t + 2); LDB1(rbA0, rbA1, t + 2); }
    __builtin_amdgcn_sched_barrier(0);
    COMP1(pC, 0);
    __builtin_amdgcn_sched_barrier(0);
    STB1(Bs[1], rbB0, rbB1);
    if (t + 2 < NS) WAIT_VM(4); else WAIT_VM(0);
    BARRIER();
    { u16* tmp = pC; pC = pN; pN = pD; pD = tmp; }
    // odd sub-step t+1
    if (t + 3 < NS) { GLLA(pD, t + 3); LDB1(rbB0, rbB1, t + 3); }
    __builtin_amdgcn_sched_barrier(0);
    COMP1(pC, 1);
    __builtin_amdgcn_sched_barrier(0);
    if (t + 2 < NS) STB1(Bs[0], rbA0, rbA1);
    if (t + 3 < NS) WAIT_VM(4); else WAIT_VM(0);
    if (t + 2 < NS) BARRIER();
    { u16* tmp = pC; pC = pN; pN = pD; pD = tmp; }
  }

  // epilogue: silu(g)*u -> bf16 act
  int rb = wm * 64 + lhi * 4;
  int cb = n0 + wn * 32 + llo;
#pragma unroll
  for (int mf = 0; mf < 4; mf++) {
#pragma unroll
    for (int r4 = 0; r4 < 4; r4++) {
      int rl = rb + mf * 16 + r4;
      if (rl < rows) {
        long rowb = (long)(baser + rl) * IDIM;
#pragma unroll
        for (int nf = 0; nf < 2; nf++) {
          float g = accg[mf][nf][r4], u = accu[mf][nf][r4];
          float av = g / (1.f + __expf(-g)) * u;
          act[rowb + cb + nf * 16] = f2bf(av);
        }
      }
    }
  }
#undef GLLA
#undef LDB1
#undef STB1
#undef COMP1
}

// ================= GEMM2: expert rows of (act Wd) =================
// Same pipeline. STORE=1: plain bf16 stores to eo (combine kernel later).
// STORE=0: atomicAdd f32 into out (fallback).
template <int STORE>
__global__ __launch_bounds__(512) void gemm2_kernel(const u16* __restrict__ act,
                                                    const float* __restrict__ wdp,
                                                    const int* __restrict__ offs,
                                                    const int* __restrict__ rtok,
                                                    const float* __restrict__ rw,
                                                    u16* __restrict__ eo,
                                                    float* __restrict__ out) {
  int d = blockIdx.x;
  int e = d & 31;
  int nt = (d >> 5) & 31;
  int mt = d >> 10;
  int off = offs[e], cnt = offs[e + 1] - off;
  int m0 = mt << 8;
  if (m0 >= cnt) return;
  int rows = cnt - m0; if (rows > 256) rows = 256;
  int baser = off + m0;
  int n0 = nt << 6;

  __shared__ __align__(16) u16 As[3][256 * 32];    // 48 KB
  __shared__ __align__(16) u32 Bs[2][64 * LDBW];   // 10 KB

  int tid = threadIdx.x;
  int ln = tid & 63, w = tid >> 6;
  int wm = w >> 1, wn = w & 1;
  int lhi = ln >> 4, llo = ln & 15;

  const u16* gA[2];
  int ldsA[2];
#pragma unroll
  for (int j = 0; j < 2; j++) {
    int idx = w * 2 + j;
    int r = idx * 16 + (ln >> 2);
    int c = ln & 3;
    int csrc = c ^ ((r >> 1) & 3);
    int rr = r < rows ? r : rows - 1;
    gA[j] = act + (long)(baser + rr) * IDIM + csrc * 8;
    ldsA[j] = idx * 1024;
  }

  int isB = (tid < 256);
  int a = tid & 15;
  int kk = (tid >> 4) & 15;
  const float* gB = wdp + (long)e * ((long)IDIM * HDIM) +
                    (long)(2 * kk) * HDIM + n0 + 4 * a;
  int fB = 2 * (a & 7);
  int wOff[4];
#pragma unroll
  for (int j = 0; j < 4; j++) wOff[j] = (4 * a + j) * LDBW + (kk ^ fB);

  int offA[4];
#pragma unroll
  for (int mf = 0; mf < 4; mf++) {
    int r = wm * 64 + mf * 16 + llo;
    offA[mf] = r * 64 + ((lhi ^ ((r >> 1) & 3)) * 16);
  }
  int dB0[2], dB1[2];
#pragma unroll
  for (int nf = 0; nf < 2; nf++) {
    int n = wn * 32 + nf * 16 + llo;
    int f = 2 * ((n >> 2) & 7);
    dB0[nf] = n * LDBW + ((4 * lhi) ^ f);
    dB1[nf] = n * LDBW + (((4 * lhi) | 2) ^ f);
  }

  f32x4 acc[4][2];
  f32x4 zz = {0.f, 0.f, 0.f, 0.f};
#pragma unroll
  for (int i = 0; i < 4; i++)
#pragma unroll
    for (int j = 0; j < 2; j++) acc[i][j] = zz;

  float4 rbA0, rbA1, rbB0, rbB1;

#define GLLA(pDst, tt)                                                \
  { gll16(gA[0] + (tt) * 32, (char*)(pDst) + ldsA[0]);                \
    gll16(gA[1] + (tt) * 32, (char*)(pDst) + ldsA[1]); }
#define LDB2(r0, r1, tt)                                              \
  { if (isB) {                                                        \
      const float* p = gB + (long)(tt) * 32 * HDIM;                   \
      r0 = *(const float4*)p; r1 = *(const float4*)(p + HDIM); } }
#define STB2(dstBs, r0, r1)                                           \
  { if (isB) {                                                        \
      u32* bb = &(dstBs)[0];                                          \
      bb[wOff[0]] = cvtpk(r0.x, r1.x);                                \
      bb[wOff[1]] = cvtpk(r0.y, r1.y);                                \
      bb[wOff[2]] = cvtpk(r0.z, r1.z);                                \
      bb[wOff[3]] = cvtpk(r0.w, r1.w); } }
#define WAITG2(nB, nNB)                                               \
  { if (isB) WAIT_VM(nB); else WAIT_VM(nNB); }
#define COMP2(pA, bsel)                                               \
  {                                                                   \
    const char* Ab = (const char*)(pA);                               \
    const u32* Bb = &Bs[bsel][0];                                     \
    s16x8 av[4];                                                      \
    _Pragma("unroll")                                                 \
    for (int mf = 0; mf < 4; mf++) av[mf] = *(const s16x8*)(Ab + offA[mf]); \
    _Pragma("unroll")                                                 \
    for (int nf = 0; nf < 2; nf++) {                                  \
      s16x8 bv = bfrag(Bb, dB0[nf], dB1[nf]);                         \
      _Pragma("unroll")                                               \
      for (int mf = 0; mf < 4; mf++)                                  \
        acc[mf][nf] = __builtin_amdgcn_mfma_f32_16x16x32_bf16(av[mf], bv, acc[mf][nf], 0, 0, 0); \
    }                                                                 \
  }

  const int NS = IDIM / 32;  // 24
  u16 *pC = As[0], *pN = As[1], *pD = As[2];

  GLLA(pC, 0); LDB2(rbA0, rbA1, 0);
  GLLA(pN, 1); LDB2(rbB0, rbB1, 1);
  __builtin_amdgcn_sched_barrier(0);
  STB2(Bs[0], rbA0, rbA1);
  WAITG2(4, 2);
  BARRIER();

  for (int t = 0; t < NS; t += 2) {
    if (t + 2 < NS) { GLLA(pD, t + 2); LDB2(rbA0, rbA1, t + 2); }
    __builtin_amdgcn_sched_barrier(0);
    COMP2(pC, 0);
    __builtin_amdgcn_sched_barrier(0);
    STB2(Bs[1], rbB0, rbB1);
    if (t + 2 < NS) { WAITG2(4, 2); } else { WAIT_VM(0); }
    BARRIER();
    { u16* tmp = pC; pC = pN; pN = pD; pD = tmp; }
    if (t + 3 < NS) { GLLA(pD, t + 3); LDB2(rbB0, rbB1, t + 3); }
    __builtin_amdgcn_sched_barrier(0);
    COMP2(pC, 1);
    __builtin_amdgcn_sched_barrier(0);
    if (t + 2 < NS) STB2(Bs[0], rbA0, rbA1);
    if (t + 3 < NS) { WAITG2(4, 2); } else { WAIT_VM(0); }
    if (t + 2 < NS) BARRIER();
    { u16* tmp = pC; pC = pN; pN = pD; pD = tmp; }
  }

  int rb = wm * 64 + lhi * 4;
  int cb = n0 + wn * 32 + llo;
#pragma unroll
  for (int mf = 0; mf < 4; mf++) {
#pragma unroll
    for (int r4 = 0; r4 < 4; r4++) {
      int rl = rb + mf * 16 + r4;
      if (rl < rows) {
        int rr = baser + rl;
        if (STORE) {
          long ob = (long)rr * HDIM + cb;
          eo[ob] = f2bf(acc[mf][0][r4]);
          eo[ob + 16] = f2bf(acc[mf][1][r4]);
        } else {
          float wt = rw[rr];
          long ob = (long)rtok[rr] * HDIM + cb;
          atomicAdd(&out[ob], acc[mf][0][r4] * wt);
          atomicAdd(&out[ob + 16], acc[mf][1][r4] * wt);
        }
      }
    }
  }
#undef GLLA
#undef LDB2
#undef STB2
#undef WAITG2
#undef COMP2
}

// ---------------- combine: out[t] = sum_k tw[t,k] * eo[row(t,k)] ----------------
__global__ __launch_bounds__(256) void combine_kernel(const u16* __restrict__ eo,
                                                      const int* __restrict__ rowmap,
                                                      const float* __restrict__ tw,
                                                      float* __restrict__ out) {
  int t = blockIdx.x;
  int h0 = threadIdx.x * 8;
  float acc[8] = {0.f, 0.f, 0.f, 0.f, 0.f, 0.f, 0.f, 0.f};
#pragma unroll
  for (int k = 0; k < KTOP; k++) {
    int r = rowmap[t * KTOP + k];
    float wt = tw[t * KTOP + k];
    u16x8 v = *(const u16x8*)(eo + (long)r * HDIM + h0);
#pragma unroll
    for (int j = 0; j < 8; j++)
      acc[j] += wt * __builtin_bit_cast(float, ((u32)v[j]) << 16);
  }
  float4 o0 = {acc[0], acc[1], acc[2], acc[3]};
  float4 o1 = {acc[4], acc[5], acc[6], acc[7]};
  *(float4*)(out + (long)t * HDIM + h0) = o0;
  *(float4*)(out + (long)t * HDIM + h0 + 4) = o1;
}

extern "C" void kernel_launch(void* const* d_in, const int* in_sizes, int n_in,
                              void* d_out, int out_size, void* d_ws, size_t ws_size,
                              hipStream_t stream) {
  const float* x = (const float*)d_in[0];
  const float* gw = (const float*)d_in[1];
  const float* wgate = (const float*)d_in[2];
  const float* wup = (const float*)d_in[3];
  const float* wdown = (const float*)d_in[4];
  float* out = (float*)d_out;

  char* ws = (char*)d_ws;
  u16* xb = (u16*)(ws + WS_XB);
  u16* act = (u16*)(ws + WS_ACT);
  int* tidx = (int*)(ws + WS_TIDX);
  float* tw = (float*)(ws + WS_TW);
  int* cnt = (int*)(ws + WS_CNT);
  int* offs = (int*)(ws + WS_OFFS);
  int* cur = (int*)(ws + WS_CUR);
  int* rtok = (int*)(ws + WS_RTOK);
  float* rw = (float*)(ws + WS_RW);
  int* rowmap = (int*)(ws + WS_RMAP);
  u16* eo = (u16*)(ws + WS_EO);
  bool storeMode = (ws_size >= (size_t)WS_NEED);

  hipMemsetAsync(cnt, 0, 128, stream);
  if (!storeMode)
    hipMemsetAsync(d_out, 0, (size_t)out_size * sizeof(float), stream);

  hipLaunchKernelGGL(router_kernel, dim3(TTOK), dim3(256), 0, stream, x, gw, xb, tidx, tw, cnt);
  hipLaunchKernelGGL(scan_kernel, dim3(1), dim3(64), 0, stream, cnt, offs, cur);
  hipLaunchKernelGGL(scatter_kernel, dim3(TTOK * KTOP / 256), dim3(256), 0, stream, tidx, tw, offs, cur, rtok, rw, rowmap);
  hipLaunchKernelGGL(gemm1_kernel, dim3(32 * 12 * 8), dim3(512), 0, stream, xb, wgate, wup, offs, rtok, act);
  if (storeMode) {
    hipLaunchKernelGGL(gemm2_kernel<1>, dim3(32 * 32 * 8), dim3(512), 0, stream, act, wdown, offs, rtok, rw, eo, out);
    hipLaunchKernelGGL(combine_kernel, dim3(TTOK), dim3(256), 0, stream, eo, rowmap, tw, out);
  } else {
    hipLaunchKernelGGL(gemm2_kernel<0>, dim3(32 * 32 * 8), dim3(512), 0, stream, act, wdown, offs, rtok, rw, eo, out);
  }
}